// Round 6
// baseline (850.635 us; speedup 1.0000x reference)
//
#include <hip/hip_runtime.h>
#include <math.h>

#define PI_HALF 1.57079632679489662f

__device__ __forceinline__ float fast_tanh(float x) {
    float e = __expf(2.f * x);
    return 1.f - 2.f * __builtin_amdgcn_rcpf(e + 1.f);
}

// ---------------- 4-qubit state helpers (compile-time masks -> registers) ----
// wire w (0..3) maps to amplitude-index bit (3-w), i.e. mask = 8 >> w.

__device__ __forceinline__ void init_state(float sr[16], float si[16]) {
#pragma unroll
    for (int i = 0; i < 16; ++i) { sr[i] = 0.f; si[i] = 0.f; }
    sr[0] = 1.f;
}

template<int M>
__device__ __forceinline__ void ry_g(float sr[16], float si[16], float c, float s) {
#pragma unroll
    for (int i = 0; i < 16; ++i) {
        if (i & M) continue;
        const int j = i | M;
        float ar = sr[i], ai = si[i], br = sr[j], bi = si[j];
        sr[i] = c * ar - s * br;  si[i] = c * ai - s * bi;
        sr[j] = s * ar + c * br;  si[j] = s * ai + c * bi;
    }
}

template<int M>
__device__ __forceinline__ void had_g(float sr[16], float si[16]) {
    const float r = 0.70710678118654752f;
#pragma unroll
    for (int i = 0; i < 16; ++i) {
        if (i & M) continue;
        const int j = i | M;
        float ar = sr[i], ai = si[i], br = sr[j], bi = si[j];
        sr[i] = (ar + br) * r;  si[i] = (ai + bi) * r;
        sr[j] = (ar - br) * r;  si[j] = (ai - bi) * r;
    }
}

template<int MC, int MT>
__device__ __forceinline__ void cnot_g(float sr[16], float si[16]) {
#pragma unroll
    for (int i = 0; i < 16; ++i) {
        if (!(i & MC) || (i & MT)) continue;
        const int j = i | MT;
        float tr = sr[i], ti = si[i];
        sr[i] = sr[j]; si[i] = si[j];
        sr[j] = tr;    si[j] = ti;
    }
}

template<int MC, int MT>
__device__ __forceinline__ void cry_g(float sr[16], float si[16], float c, float s) {
#pragma unroll
    for (int i = 0; i < 16; ++i) {
        if (!(i & MC) || (i & MT)) continue;
        const int j = i | MT;
        float ar = sr[i], ai = si[i], br = sr[j], bi = si[j];
        sr[i] = c * ar - s * br;  si[i] = c * ai - s * bi;
        sr[j] = s * ar + c * br;  si[j] = s * ai + c * bi;
    }
}

template<int M>
__device__ __forceinline__ void rot_pre(float sr[16], float si[16], const float* __restrict__ u) {
    const float u00r = u[0], u00i = u[1], u01r = u[2], u01i = u[3];
    const float u10r = u[4], u10i = u[5], u11r = u[6], u11i = u[7];
#pragma unroll
    for (int i = 0; i < 16; ++i) {
        if (i & M) continue;
        const int j = i | M;
        float ar = sr[i], ai = si[i], br = sr[j], bi = si[j];
        sr[i] = u00r * ar - u00i * ai + u01r * br - u01i * bi;
        si[i] = u00r * ai + u00i * ar + u01r * bi + u01i * br;
        sr[j] = u10r * ar - u10i * ai + u11r * br - u11i * bi;
        si[j] = u10r * ai + u10i * ar + u11r * bi + u11i * br;
    }
}

__device__ __forceinline__ void zexp_g(const float sr[16], const float si[16], float z[4]) {
    float p[16];
#pragma unroll
    for (int i = 0; i < 16; ++i) p[i] = sr[i] * sr[i] + si[i] * si[i];
    z[0] = z[1] = z[2] = z[3] = 0.f;
#pragma unroll
    for (int i = 0; i < 16; ++i) {
        z[0] += (i & 8) ? -p[i] : p[i];
        z[1] += (i & 4) ? -p[i] : p[i];
        z[2] += (i & 2) ? -p[i] : p[i];
        z[3] += (i & 1) ? -p[i] : p[i];
    }
}

// ---------------- setup: rot matrices + fused output matrix + sumexp[0]=1 ----
__global__ void k_setup(const float* __restrict__ entp, const float* __restrict__ attqp,
                        const float* __restrict__ pparm,
                        const float* __restrict__ outW, const float* __restrict__ outb,
                        const float* __restrict__ poW, const float* __restrict__ pob,
                        float* __restrict__ rotbuf, float* __restrict__ M,
                        float* __restrict__ v, float* __restrict__ sumexp) {
    const int t = threadIdx.x;
    if (t < 36) {
        const float* p;
        if (t < 16)      p = entp  + t * 3;
        else if (t < 24) p = attqp + (t - 16) * 3;
        else             p = pparm + (t - 24) * 3;
        float phi = p[0], theta = p[1], omega = p[2];
        float st, ct; sincosf(0.5f * theta, &st, &ct);
        float sp, cp; sincosf(0.5f * (phi + omega), &sp, &cp);
        float sm, cm; sincosf(0.5f * (phi - omega), &sm, &cm);
        float* u = rotbuf + t * 8;
        u[0] =  ct * cp;  u[1] = -ct * sp;
        u[2] = -st * cm;  u[3] = -st * sm;
        u[4] =  st * cm;  u[5] = -st * sm;
        u[6] =  ct * cp;  u[7] =  ct * sp;
    } else if (t >= 64 && t < 192) {
        int t2 = t - 64;
        int o = t2 >> 2, i = t2 & 3;
        float acc = 0.f;
        for (int j = 0; j < 128; ++j) acc += outW[o * 128 + j] * poW[j * 4 + i];
        M[t2] = acc;
    } else if (t >= 192 && t < 224) {
        int o = t - 192;
        float acc = outb[o];
        for (int j = 0; j < 128; ++j) acc += outW[o * 128 + j] * pob[j];
        v[o] = acc;
    } else if (t == 255) {
        sumexp[0] = 1.0f;  // layer-0 h is unnormalized (scale 1)
    }
}

// transpose weights: tWin[64][128] <- Win[128][64]; tl{0,1}[128][128] <- linW[l][o][k]
__global__ void k_tr(const float* __restrict__ Win, const float* __restrict__ l0,
                     const float* __restrict__ l1, float* __restrict__ tWin,
                     float* __restrict__ tl0, float* __restrict__ tl1) {
    int i = blockIdx.x * 256 + threadIdx.x;
    if (i < 64 * 128) {
        int k = i >> 7, o = i & 127;
        tWin[i] = Win[o * 64 + k];
    }
    int j = i - 64 * 128;
    if (j >= 0 && j < 128 * 128) {
        int k = j >> 7, o = j & 127;
        tl0[j] = l0[o * 128 + k];
        tl1[j] = l1[o * 128 + k];
    }
}

// ---------------- dst binning (edge_index layer-invariant: built once) -------

__global__ void k_hist(const int* __restrict__ ei, int* __restrict__ cnt, int E, int EP) {
    int e = blockIdx.x * blockDim.x + threadIdx.x;
    if (e >= EP) return;
    int d_ = (e < E) ? ei[E + e] : e - E;
    atomicAdd(&cnt[d_], 1);
}

__global__ void k_scan(const int* __restrict__ cnt, int* __restrict__ off,
                       int* __restrict__ cur, int N) {
    __shared__ int tot[1024];
    const int t = threadIdx.x;
    const int chunk = (N + 1023) >> 10;
    const int s0 = t * chunk;
    const int s1 = min(s0 + chunk, N);
    int sum = 0;
    for (int i = s0; i < s1; ++i) sum += cnt[i];
    tot[t] = sum;
    __syncthreads();
    for (int d = 1; d < 1024; d <<= 1) {
        int v = (t >= d) ? tot[t - d] : 0;
        __syncthreads();
        tot[t] += v;
        __syncthreads();
    }
    int run = (t == 0) ? 0 : tot[t - 1];
    for (int i = s0; i < s1; ++i) {
        off[i] = run; cur[i] = run;
        run += cnt[i];
    }
}

__global__ void k_fill(const int* __restrict__ ei, int* __restrict__ cur,
                       int* __restrict__ srcs, int E, int EP) {
    int e = blockIdx.x * blockDim.x + threadIdx.x;
    if (e >= EP) return;
    int s_, d_;
    if (e < E) { s_ = ei[e]; d_ = ei[E + e]; } else { s_ = d_ = e - E; }
    int pos = atomicAdd(&cur[d_], 1);
    srcs[pos] = s_;
}

// ---------------- GEMM-style node kernels (8-out x 4-node register tiles) ----

// h = relu(x @ W_in^T + b_in); 64 nodes/block, 256 thr; tW[k][o] coalesced
#define XS 68
__global__ __launch_bounds__(256) void k_in(
        const float* __restrict__ x, const float* __restrict__ tW,
        const float* __restrict__ b, float* __restrict__ h, int N) {
    __shared__ float xs[64 * XS];
    const int base = blockIdx.x * 64;
    const int tid = threadIdx.x;
    for (int idx = tid; idx < 64 * 64; idx += 256) {
        int n = base + (idx >> 6);
        xs[(idx >> 6) * XS + (idx & 63)] = (n < N) ? x[(size_t)n * 64 + (idx & 63)] : 0.f;
    }
    __syncthreads();
    const int og = tid & 15;   // 16 out-groups x 8 outs
    const int ng = tid >> 4;   // 16 node-groups x 4 nodes
    float acc[8][4];
#pragma unroll
    for (int r = 0; r < 8; ++r)
#pragma unroll
        for (int n = 0; n < 4; ++n) acc[r][n] = 0.f;
    for (int k4 = 0; k4 < 16; ++k4) {
        float4 hv[4];
#pragma unroll
        for (int n = 0; n < 4; ++n) hv[n] = *(const float4*)&xs[(ng * 4 + n) * XS + k4 * 4];
#pragma unroll
        for (int j = 0; j < 4; ++j) {
            const float* wr = tW + (k4 * 4 + j) * 128 + og * 8;
            float4 w0 = *(const float4*)wr;
            float4 w1 = *(const float4*)(wr + 4);
#pragma unroll
            for (int n = 0; n < 4; ++n) {
                float hj = (&hv[n].x)[j];
                acc[0][n] += w0.x * hj; acc[1][n] += w0.y * hj;
                acc[2][n] += w0.z * hj; acc[3][n] += w0.w * hj;
                acc[4][n] += w1.x * hj; acc[5][n] += w1.y * hj;
                acc[6][n] += w1.z * hj; acc[7][n] += w1.w * hj;
            }
        }
    }
    float4 b0 = *(const float4*)&b[og * 8];
    float4 b1 = *(const float4*)&b[og * 8 + 4];
#pragma unroll
    for (int n = 0; n < 4; ++n) {
        int node = base + ng * 4 + n;
        if (node < N) {
            float4 o0 = make_float4(fmaxf(acc[0][n] + b0.x, 0.f), fmaxf(acc[1][n] + b0.y, 0.f),
                                    fmaxf(acc[2][n] + b0.z, 0.f), fmaxf(acc[3][n] + b0.w, 0.f));
            float4 o1 = make_float4(fmaxf(acc[4][n] + b1.x, 0.f), fmaxf(acc[5][n] + b1.y, 0.f),
                                    fmaxf(acc[6][n] + b1.z, 0.f), fmaxf(acc[7][n] + b1.w, 0.f));
            *(float4*)&h[(size_t)node * 128 + og * 8] = o0;
            *(float4*)&h[(size_t)node * 128 + og * 8 + 4] = o1;
        }
    }
}

// entangle circuit per node; h scaled by invS = rcp(sumexp[l])
__global__ void k_ent(const float* __restrict__ h, const float* __restrict__ rotE,
                      const float* __restrict__ pS, float* __restrict__ xq, int N) {
    int n = blockIdx.x * blockDim.x + threadIdx.x;
    if (n >= N) return;
    const float invS = __builtin_amdgcn_rcpf(pS[0]);
    float4 hv = *(const float4*)&h[(size_t)n * 128];
    float sr[16], si[16];
    init_state(sr, si);
    { float s, c; __sincosf(fast_tanh(hv.x * invS) * (0.5f * PI_HALF), &s, &c); ry_g<8>(sr, si, c, s); }
    { float s, c; __sincosf(fast_tanh(hv.y * invS) * (0.5f * PI_HALF), &s, &c); ry_g<4>(sr, si, c, s); }
    { float s, c; __sincosf(fast_tanh(hv.z * invS) * (0.5f * PI_HALF), &s, &c); ry_g<2>(sr, si, c, s); }
    { float s, c; __sincosf(fast_tanh(hv.w * invS) * (0.5f * PI_HALF), &s, &c); ry_g<1>(sr, si, c, s); }
#pragma unroll
    for (int l = 0; l < 2; ++l) {
        cnot_g<8, 4>(sr, si); cnot_g<4, 2>(sr, si); cnot_g<2, 1>(sr, si);
        const float* P = rotE + l * 32;
        rot_pre<8>(sr, si, P);
        rot_pre<4>(sr, si, P + 8);
        rot_pre<2>(sr, si, P + 16);
        rot_pre<1>(sr, si, P + 24);
        cnot_g<8, 1>(sr, si);  // CNOT(0, 3)
    }
    float z[4]; zexp_g(sr, si, z);
    *(float4*)&xq[(size_t)n * 4] = make_float4(z[0], z[1], z[2], z[3]);
}

// x_comb + q/k (c,s): 64 nodes/block, 256 thr, 8x4 register tile, tlinW[k][o]
#define HS 132
__global__ __launch_bounds__(256) void k_lin(
        const float* __restrict__ h, const float* __restrict__ xq,
        const float* __restrict__ tlinW, const float* __restrict__ linb,
        const float* __restrict__ qpW, const float* __restrict__ qpb,
        const float* __restrict__ aqW, const float* __restrict__ aqb,
        const float* __restrict__ akW, const float* __restrict__ akb,
        const float* __restrict__ pS,
        float* __restrict__ xcomb, float* __restrict__ qbuf,
        float* __restrict__ kbuf, int N) {
    __shared__ float hs[64 * HS];
    __shared__ float zS[64 * 4];
    const int base = blockIdx.x * 64;
    const int tid = threadIdx.x;
    const float invS = __builtin_amdgcn_rcpf(pS[0]);
    for (int idx = tid; idx < 64 * 128; idx += 256) {
        int n = base + (idx >> 7);
        hs[(idx >> 7) * HS + (idx & 127)] =
            (n < N) ? h[(size_t)n * 128 + (idx & 127)] * invS : 0.f;
    }
    {
        int n = base + (tid >> 2);
        zS[tid] = (n < N) ? xq[(size_t)n * 4 + (tid & 3)] : 0.f;
    }
    __syncthreads();

    const int og = tid & 15;
    const int ng = tid >> 4;
    float acc[8][4];
#pragma unroll
    for (int r = 0; r < 8; ++r)
#pragma unroll
        for (int n = 0; n < 4; ++n) acc[r][n] = 0.f;
    for (int k4 = 0; k4 < 32; ++k4) {
        float4 hv[4];
#pragma unroll
        for (int n = 0; n < 4; ++n) hv[n] = *(const float4*)&hs[(ng * 4 + n) * HS + k4 * 4];
#pragma unroll
        for (int j = 0; j < 4; ++j) {
            const float* wr = tlinW + (k4 * 4 + j) * 128 + og * 8;
            float4 w0 = *(const float4*)wr;
            float4 w1 = *(const float4*)(wr + 4);
#pragma unroll
            for (int n = 0; n < 4; ++n) {
                float hj = (&hv[n].x)[j];
                acc[0][n] += w0.x * hj; acc[1][n] += w0.y * hj;
                acc[2][n] += w0.z * hj; acc[3][n] += w0.w * hj;
                acc[4][n] += w1.x * hj; acc[5][n] += w1.y * hj;
                acc[6][n] += w1.z * hj; acc[7][n] += w1.w * hj;
            }
        }
    }

    // q/k dots: thread -> node (tid>>2), qi (tid&3); one q-dot and one k-dot each
    {
        const int nl = tid >> 2;
        const int qi = tid & 3;
        const float4* Wq4 = (const float4*)(aqW + qi * 128);
        const float4* Wk4 = (const float4*)(akW + qi * 128);
        float dq = aqb[qi], dk = akb[qi];
        for (int c4 = 0; c4 < 32; ++c4) {
            float4 hv = *(const float4*)&hs[nl * HS + c4 * 4];
            float4 wq = Wq4[c4], wk = Wk4[c4];
            dq += wq.x * hv.x + wq.y * hv.y + wq.z * hv.z + wq.w * hv.w;
            dk += wk.x * hv.x + wk.y * hv.y + wk.z * hv.z + wk.w * hv.w;
        }
        int node = base + nl;
        if (node < N) {
            float s, c;
            __sincosf(fast_tanh(dq) * (0.5f * PI_HALF), &s, &c);
            qbuf[(size_t)node * 8 + qi * 2] = c;
            qbuf[(size_t)node * 8 + qi * 2 + 1] = s;
            __sincosf(fast_tanh(dk) * (0.5f * PI_HALF), &s, &c);
            kbuf[(size_t)node * 8 + qi * 2] = c;
            kbuf[(size_t)node * 8 + qi * 2 + 1] = s;
        }
    }

    const float4 lb0 = *(const float4*)&linb[og * 8];
    const float4 lb1 = *(const float4*)&linb[og * 8 + 4];
    const float4 qb0 = *(const float4*)&qpb[og * 8];
    const float4 qb1 = *(const float4*)&qpb[og * 8 + 4];
#pragma unroll
    for (int n = 0; n < 4; ++n) {
        int node = base + ng * 4 + n;
        if (node < N) {
            float4 z = *(const float4*)&zS[(ng * 4 + n) * 4];
            float4 o0, o1;
            const float* qw = qpW + og * 32;  // 8 rows x 4
            o0.x = acc[0][n] + lb0.x + qb0.x + qw[0]*z.x + qw[1]*z.y + qw[2]*z.z + qw[3]*z.w;
            o0.y = acc[1][n] + lb0.y + qb0.y + qw[4]*z.x + qw[5]*z.y + qw[6]*z.z + qw[7]*z.w;
            o0.z = acc[2][n] + lb0.z + qb0.z + qw[8]*z.x + qw[9]*z.y + qw[10]*z.z + qw[11]*z.w;
            o0.w = acc[3][n] + lb0.w + qb0.w + qw[12]*z.x + qw[13]*z.y + qw[14]*z.z + qw[15]*z.w;
            o1.x = acc[4][n] + lb1.x + qb1.x + qw[16]*z.x + qw[17]*z.y + qw[18]*z.z + qw[19]*z.w;
            o1.y = acc[5][n] + lb1.y + qb1.y + qw[20]*z.x + qw[21]*z.y + qw[22]*z.z + qw[23]*z.w;
            o1.z = acc[6][n] + lb1.z + qb1.z + qw[24]*z.x + qw[25]*z.y + qw[26]*z.z + qw[27]*z.w;
            o1.w = acc[7][n] + lb1.w + qb1.w + qw[28]*z.x + qw[29]*z.y + qw[30]*z.z + qw[31]*z.w;
            *(float4*)&xcomb[(size_t)node * 128 + og * 8] = o0;
            *(float4*)&xcomb[(size_t)node * 128 + og * 8 + 4] = o1;
        }
    }
}

// fused attention + gather: one block per dst; k-row is block-uniform.
// writes UNNORMALIZED g = relu(sum exp(sc)*xcomb[src]) and accumulates sumexp.
__global__ __launch_bounds__(128) void k_gatt(
        const float* __restrict__ qb, const float* __restrict__ kb,
        const int* __restrict__ srcs, const int* __restrict__ off,
        const int* __restrict__ cnt, const float* __restrict__ xcomb,
        const float* __restrict__ RA, float* __restrict__ g,
        float* __restrict__ sumexp_next, int N) {
    __shared__ int sS[128];
    __shared__ float wS[128];
    __shared__ float red[2];
    const int b = blockIdx.x;
    const int tid = threadIdx.x;
    const int start = off[b];
    const int num = cnt[b];
    float4 ka = *(const float4*)&kb[(size_t)b * 8];
    float4 kc = *(const float4*)&kb[(size_t)b * 8 + 4];
    float acc = 0.f, exsum = 0.f;
    for (int base2 = 0; base2 < num; base2 += 128) {
        int m = min(128, num - base2);
        if (tid < m) {
            int s_ = srcs[start + base2 + tid];
            float4 qa = *(const float4*)&qb[(size_t)s_ * 8];
            float4 qc = *(const float4*)&qb[(size_t)s_ * 8 + 4];
            float sr[16], si[16];
            init_state(sr, si);
            ry_g<8>(sr, si, qa.x, qa.y);
            ry_g<4>(sr, si, qa.z, qa.w);
            ry_g<2>(sr, si, qc.x, qc.y);
            ry_g<1>(sr, si, qc.z, qc.w);
            had_g<8>(sr, si); had_g<4>(sr, si); had_g<2>(sr, si); had_g<1>(sr, si);
            cry_g<8, 4>(sr, si, ka.x, ka.y);
            cry_g<4, 2>(sr, si, ka.z, ka.w);
            cry_g<2, 1>(sr, si, kc.x, kc.y);
            cry_g<1, 8>(sr, si, kc.z, kc.w);
            rot_pre<8>(sr, si, RA);
            rot_pre<4>(sr, si, RA + 8);
            rot_pre<2>(sr, si, RA + 16);
            rot_pre<1>(sr, si, RA + 24);
            float z[4]; zexp_g(sr, si, z);
            float sc = 0.25f * (z[0] + z[1] + z[2] + z[3]);
            float ex = __expf(sc);
            sS[tid] = s_; wS[tid] = ex;
            exsum += ex;
        }
        __syncthreads();
        for (int i = 0; i < m; ++i)
            acc += wS[i] * xcomb[(size_t)sS[i] * 128 + tid];
        __syncthreads();
    }
    g[(size_t)b * 128 + tid] = fmaxf(acc, 0.f);
#pragma unroll
    for (int d = 32; d > 0; d >>= 1) exsum += __shfl_down(exsum, d, 64);
    if ((tid & 63) == 0) red[tid >> 6] = exsum;
    __syncthreads();
    if (tid == 0) atomicAdd(sumexp_next, red[0] + red[1]);
}

// pq (c,s) pairs; h scaled by invS; 32 nodes/block, 128 thr
__global__ void k_pq(const float* __restrict__ h, const float* __restrict__ piW,
                     const float* __restrict__ pib, const float* __restrict__ pS,
                     float* __restrict__ pq8, int N) {
    __shared__ float hs[32 * HS];
    const int base = blockIdx.x * 32;
    const int tid = threadIdx.x;  // 128
    const float invS = __builtin_amdgcn_rcpf(pS[0]);
    for (int idx = tid; idx < 32 * 128; idx += 128) {
        int n = base + (idx >> 7);
        hs[(idx >> 7) * HS + (idx & 127)] =
            (n < N) ? h[(size_t)n * 128 + (idx & 127)] * invS : 0.f;
    }
    __syncthreads();
    const int nl = tid >> 2;
    const int i  = tid & 3;
    float dot = pib[i];
    const float4* w4 = (const float4*)(piW + i * 128);
    for (int c4 = 0; c4 < 32; ++c4) {
        float4 w = w4[c4];
        float4 hv = *(const float4*)&hs[nl * HS + c4 * 4];
        dot += w.x * hv.x + w.y * hv.y + w.z * hv.z + w.w * hv.w;
    }
    int node = base + nl;
    if (node < N) {
        float s, c; __sincosf(fast_tanh(dot) * (0.5f * PI_HALF), &s, &c);
        pq8[(size_t)node * 8 + i * 2]     = c;
        pq8[(size_t)node * 8 + i * 2 + 1] = s;
    }
}

// path circuit per node + epilogue out = M@z + v (coalesced via LDS staging)
__global__ void k_pathc(const float* __restrict__ pq8, const float* __restrict__ RP,
                        const float* __restrict__ M, const float* __restrict__ v,
                        float* __restrict__ out, int N) {
    __shared__ float zS[256 * 4];
    __shared__ float MS[128];
    __shared__ float vS[32];
    const int tid = threadIdx.x;  // 256
    if (tid < 128) MS[tid] = M[tid];
    else if (tid < 160) vS[tid - 128] = v[tid - 128];
    __syncthreads();
    const int base = blockIdx.x * 256;
    const int n = base + tid;
    if (n < N) {
        float4 pa = *(const float4*)&pq8[(size_t)n * 8];
        float4 pc = *(const float4*)&pq8[(size_t)n * 8 + 4];
        float sr[16], si[16];
        init_state(sr, si);
        had_g<8>(sr, si); had_g<4>(sr, si); had_g<2>(sr, si); had_g<1>(sr, si);
        ry_g<8>(sr, si, pa.x, pa.y);
        ry_g<4>(sr, si, pa.z, pa.w);
        ry_g<2>(sr, si, pc.x, pc.y);
        ry_g<1>(sr, si, pc.z, pc.w);
#pragma unroll
        for (int l = 0; l < 3; ++l) {
            const float* P = RP + l * 32;
            rot_pre<8>(sr, si, P);
            rot_pre<4>(sr, si, P + 8);
            rot_pre<2>(sr, si, P + 16);
            rot_pre<1>(sr, si, P + 24);
            cnot_g<8, 4>(sr, si); cnot_g<4, 2>(sr, si); cnot_g<2, 1>(sr, si);
        }
        float z[4]; zexp_g(sr, si, z);
        zS[tid * 4 + 0] = z[0]; zS[tid * 4 + 1] = z[1];
        zS[tid * 4 + 2] = z[2]; zS[tid * 4 + 3] = z[3];
    }
    __syncthreads();
#pragma unroll
    for (int k = 0; k < 32; ++k) {
        int flat = k * 256 + tid;
        int nl = flat >> 5;
        int o = flat & 31;
        int node = base + nl;
        if (node < N) {
            out[(size_t)node * 32 + o] = vS[o]
                + MS[o * 4 + 0] * zS[nl * 4 + 0] + MS[o * 4 + 1] * zS[nl * 4 + 1]
                + MS[o * 4 + 2] * zS[nl * 4 + 2] + MS[o * 4 + 3] * zS[nl * 4 + 3];
        }
    }
}

// ---------------- launch ----------------------------------------------------

extern "C" void kernel_launch(void* const* d_in, const int* in_sizes, int n_in,
                              void* d_out, int out_size, void* d_ws, size_t ws_size,
                              hipStream_t stream) {
    const float* x     = (const float*)d_in[0];
    const float* W_in  = (const float*)d_in[1];
    const float* b_in  = (const float*)d_in[2];
    const float* linW  = (const float*)d_in[3];
    const float* linb  = (const float*)d_in[4];
    const float* qpW   = (const float*)d_in[5];
    const float* qpb   = (const float*)d_in[6];
    const float* entp  = (const float*)d_in[7];
    const float* aqW   = (const float*)d_in[8];
    const float* aqb   = (const float*)d_in[9];
    const float* akW   = (const float*)d_in[10];
    const float* akb   = (const float*)d_in[11];
    const float* attqp = (const float*)d_in[12];
    const float* pparm = (const float*)d_in[13];
    const float* piW   = (const float*)d_in[14];
    const float* pib   = (const float*)d_in[15];
    const float* poW   = (const float*)d_in[16];
    const float* pob   = (const float*)d_in[17];
    const float* outW  = (const float*)d_in[18];
    const float* outb  = (const float*)d_in[19];
    const int*   ei    = (const int*)d_in[20];

    const int N  = in_sizes[0] / 64;   // 20000
    const int E  = in_sizes[20] / 2;   // 300000
    const int EP = E + N;              // self-loops appended

    float* ws     = (float*)d_ws;
    float* h      = ws;
    float* xcomb  = h      + (size_t)N * 128;
    float* xq     = xcomb  + (size_t)N * 128;
    float* qbuf   = xq     + (size_t)N * 4;
    float* kbuf   = qbuf   + (size_t)N * 8;
    float* pq8    = kbuf   + (size_t)N * 8;
    float* tWin   = pq8    + (size_t)N * 8;
    float* tl0    = tWin   + 64 * 128;
    float* tl1    = tl0    + 128 * 128;
    float* rotbuf = tl1    + 128 * 128;
    float* Mm     = rotbuf + 36 * 8;
    float* vv     = Mm + 128;
    int*   cnt    = (int*)(vv + 32);
    float* sumexp = (float*)(cnt + N);   // 3 slots: [0]=1.0, [1]=layer0, [2]=layer1
    int*   off    = (int*)(sumexp + 4);
    int*   cur    = off + N;
    int*   srcs   = cur + N;

    const float* rotE = rotbuf;          // 16 matrices
    const float* rotA = rotbuf + 128;    // 8 matrices
    const float* rotP = rotbuf + 192;    // 12 matrices

    const int nb64 = (N + 63) / 64;
    const int ebl  = (EP + 255) / 256;

    hipMemsetAsync(cnt, 0, (size_t)(N + 4) * sizeof(int), stream);
    k_hist<<<ebl, 256, 0, stream>>>(ei, cnt, E, EP);
    k_scan<<<1, 1024, 0, stream>>>(cnt, off, cur, N);
    k_fill<<<ebl, 256, 0, stream>>>(ei, cur, srcs, E, EP);
    k_setup<<<1, 256, 0, stream>>>(entp, attqp, pparm, outW, outb, poW, pob,
                                   rotbuf, Mm, vv, sumexp);
    k_tr<<<96, 256, 0, stream>>>(W_in, linW, linW + 128 * 128, tWin, tl0, tl1);
    k_in<<<nb64, 256, 0, stream>>>(x, tWin, b_in, h, N);

    for (int l = 0; l < 2; ++l) {
        const float* tl = (l == 0) ? tl0 : tl1;
        k_ent<<<(N + 255) / 256, 256, 0, stream>>>(h, rotE + l * 64, sumexp + l, xq, N);
        k_lin<<<nb64, 256, 0, stream>>>(h, xq, tl,
            linb + l * 128,
            qpW + (size_t)l * 128 * 4, qpb + l * 128,
            aqW + (size_t)l * 4 * 128, aqb + l * 4,
            akW + (size_t)l * 4 * 128, akb + l * 4,
            sumexp + l, xcomb, qbuf, kbuf, N);
        k_gatt<<<N, 128, 0, stream>>>(qbuf, kbuf, srcs, off, cnt, xcomb,
                                      rotA + l * 32, h, sumexp + l + 1, N);
    }

    k_pq<<<(N + 31) / 32, 128, 0, stream>>>(h, piW, pib, sumexp + 2, pq8, N);
    k_pathc<<<(N + 255) / 256, 256, 0, stream>>>(pq8, rotP, Mm, vv, (float*)d_out, N);
}

// Round 7
// 420.346 us; speedup vs baseline: 2.0237x; 2.0237x over previous
//
#include <hip/hip_runtime.h>
#include <math.h>

#define PI_HALF 1.57079632679489662f

__device__ __forceinline__ float fast_tanh(float x) {
    float e = __expf(2.f * x);
    return 1.f - 2.f * __builtin_amdgcn_rcpf(e + 1.f);
}

// ---------------- 4-qubit state helpers (compile-time masks -> registers) ----
// wire w (0..3) maps to amplitude-index bit (3-w), i.e. mask = 8 >> w.

__device__ __forceinline__ void init_state(float sr[16], float si[16]) {
#pragma unroll
    for (int i = 0; i < 16; ++i) { sr[i] = 0.f; si[i] = 0.f; }
    sr[0] = 1.f;
}

template<int M>
__device__ __forceinline__ void ry_g(float sr[16], float si[16], float c, float s) {
#pragma unroll
    for (int i = 0; i < 16; ++i) {
        if (i & M) continue;
        const int j = i | M;
        float ar = sr[i], ai = si[i], br = sr[j], bi = si[j];
        sr[i] = c * ar - s * br;  si[i] = c * ai - s * bi;
        sr[j] = s * ar + c * br;  si[j] = s * ai + c * bi;
    }
}

template<int M>
__device__ __forceinline__ void had_g(float sr[16], float si[16]) {
    const float r = 0.70710678118654752f;
#pragma unroll
    for (int i = 0; i < 16; ++i) {
        if (i & M) continue;
        const int j = i | M;
        float ar = sr[i], ai = si[i], br = sr[j], bi = si[j];
        sr[i] = (ar + br) * r;  si[i] = (ai + bi) * r;
        sr[j] = (ar - br) * r;  si[j] = (ai - bi) * r;
    }
}

template<int MC, int MT>
__device__ __forceinline__ void cnot_g(float sr[16], float si[16]) {
#pragma unroll
    for (int i = 0; i < 16; ++i) {
        if (!(i & MC) || (i & MT)) continue;
        const int j = i | MT;
        float tr = sr[i], ti = si[i];
        sr[i] = sr[j]; si[i] = si[j];
        sr[j] = tr;    si[j] = ti;
    }
}

template<int MC, int MT>
__device__ __forceinline__ void cry_g(float sr[16], float si[16], float c, float s) {
#pragma unroll
    for (int i = 0; i < 16; ++i) {
        if (!(i & MC) || (i & MT)) continue;
        const int j = i | MT;
        float ar = sr[i], ai = si[i], br = sr[j], bi = si[j];
        sr[i] = c * ar - s * br;  si[i] = c * ai - s * bi;
        sr[j] = s * ar + c * br;  si[j] = s * ai + c * bi;
    }
}

template<int M>
__device__ __forceinline__ void rot_pre(float sr[16], float si[16], const float* __restrict__ u) {
    const float u00r = u[0], u00i = u[1], u01r = u[2], u01i = u[3];
    const float u10r = u[4], u10i = u[5], u11r = u[6], u11i = u[7];
#pragma unroll
    for (int i = 0; i < 16; ++i) {
        if (i & M) continue;
        const int j = i | M;
        float ar = sr[i], ai = si[i], br = sr[j], bi = si[j];
        sr[i] = u00r * ar - u00i * ai + u01r * br - u01i * bi;
        si[i] = u00r * ai + u00i * ar + u01r * bi + u01i * br;
        sr[j] = u10r * ar - u10i * ai + u11r * br - u11i * bi;
        si[j] = u10r * ai + u10i * ar + u11r * bi + u11i * br;
    }
}

__device__ __forceinline__ void zexp_g(const float sr[16], const float si[16], float z[4]) {
    float p[16];
#pragma unroll
    for (int i = 0; i < 16; ++i) p[i] = sr[i] * sr[i] + si[i] * si[i];
    z[0] = z[1] = z[2] = z[3] = 0.f;
#pragma unroll
    for (int i = 0; i < 16; ++i) {
        z[0] += (i & 8) ? -p[i] : p[i];
        z[1] += (i & 4) ? -p[i] : p[i];
        z[2] += (i & 2) ? -p[i] : p[i];
        z[3] += (i & 1) ? -p[i] : p[i];
    }
}

// ---------------- setup: rot matrices + fused output matrix + sumexp[0]=1 ----
__global__ void k_setup(const float* __restrict__ entp, const float* __restrict__ attqp,
                        const float* __restrict__ pparm,
                        const float* __restrict__ outW, const float* __restrict__ outb,
                        const float* __restrict__ poW, const float* __restrict__ pob,
                        float* __restrict__ rotbuf, float* __restrict__ M,
                        float* __restrict__ v, float* __restrict__ sumexp) {
    const int t = threadIdx.x;
    if (t < 36) {
        const float* p;
        if (t < 16)      p = entp  + t * 3;
        else if (t < 24) p = attqp + (t - 16) * 3;
        else             p = pparm + (t - 24) * 3;
        float phi = p[0], theta = p[1], omega = p[2];
        float st, ct; sincosf(0.5f * theta, &st, &ct);
        float sp, cp; sincosf(0.5f * (phi + omega), &sp, &cp);
        float sm, cm; sincosf(0.5f * (phi - omega), &sm, &cm);
        float* u = rotbuf + t * 8;
        u[0] =  ct * cp;  u[1] = -ct * sp;
        u[2] = -st * cm;  u[3] = -st * sm;
        u[4] =  st * cm;  u[5] = -st * sm;
        u[6] =  ct * cp;  u[7] =  ct * sp;
    } else if (t >= 64 && t < 192) {
        int t2 = t - 64;
        int o = t2 >> 2, i = t2 & 3;
        float acc = 0.f;
        for (int j = 0; j < 128; ++j) acc += outW[o * 128 + j] * poW[j * 4 + i];
        M[t2] = acc;
    } else if (t >= 192 && t < 224) {
        int o = t - 192;
        float acc = outb[o];
        for (int j = 0; j < 128; ++j) acc += outW[o * 128 + j] * pob[j];
        v[o] = acc;
    } else if (t == 255) {
        sumexp[0] = 1.0f;  // layer-0 h is unnormalized (scale 1)
    }
}

// transpose weights: tWin[64][128] <- Win[128][64]; tl{0,1}[128][128] <- linW[l][o][k]
__global__ void k_tr(const float* __restrict__ Win, const float* __restrict__ l0,
                     const float* __restrict__ l1, float* __restrict__ tWin,
                     float* __restrict__ tl0, float* __restrict__ tl1) {
    int i = blockIdx.x * 256 + threadIdx.x;
    if (i < 64 * 128) {
        int k = i >> 7, o = i & 127;
        tWin[i] = Win[o * 64 + k];
    }
    int j = i - 64 * 128;
    if (j >= 0 && j < 128 * 128) {
        int k = j >> 7, o = j & 127;
        tl0[j] = l0[o * 128 + k];
        tl1[j] = l1[o * 128 + k];
    }
}

// ---------------- dst binning (edge_index layer-invariant: built once) -------

__global__ void k_hist(const int* __restrict__ ei, int* __restrict__ cnt, int E, int EP) {
    int e = blockIdx.x * blockDim.x + threadIdx.x;
    if (e >= EP) return;
    int d_ = (e < E) ? ei[E + e] : e - E;
    atomicAdd(&cnt[d_], 1);
}

__global__ void k_scan(const int* __restrict__ cnt, int* __restrict__ off,
                       int* __restrict__ cur, int N) {
    __shared__ int tot[1024];
    const int t = threadIdx.x;
    const int chunk = (N + 1023) >> 10;
    const int s0 = t * chunk;
    const int s1 = min(s0 + chunk, N);
    int sum = 0;
    for (int i = s0; i < s1; ++i) sum += cnt[i];
    tot[t] = sum;
    __syncthreads();
    for (int d = 1; d < 1024; d <<= 1) {
        int v = (t >= d) ? tot[t - d] : 0;
        __syncthreads();
        tot[t] += v;
        __syncthreads();
    }
    int run = (t == 0) ? 0 : tot[t - 1];
    for (int i = s0; i < s1; ++i) {
        off[i] = run; cur[i] = run;
        run += cnt[i];
    }
}

__global__ void k_fill(const int* __restrict__ ei, int* __restrict__ cur,
                       int* __restrict__ srcs, int* __restrict__ dsts, int E, int EP) {
    int e = blockIdx.x * blockDim.x + threadIdx.x;
    if (e >= EP) return;
    int s_, d_;
    if (e < E) { s_ = ei[e]; d_ = ei[E + e]; } else { s_ = d_ = e - E; }
    int pos = atomicAdd(&cur[d_], 1);
    srcs[pos] = s_;
    dsts[pos] = d_;
}

// ---------------- GEMM-style node kernels (8-out x 4-node register tiles) ----

// h = relu(x @ W_in^T + b_in); 64 nodes/block, 256 thr; tW[k][o] coalesced
#define XS 68
__global__ __launch_bounds__(256) void k_in(
        const float* __restrict__ x, const float* __restrict__ tW,
        const float* __restrict__ b, float* __restrict__ h, int N) {
    __shared__ float xs[64 * XS];
    const int base = blockIdx.x * 64;
    const int tid = threadIdx.x;
    for (int idx = tid; idx < 64 * 64; idx += 256) {
        int n = base + (idx >> 6);
        xs[(idx >> 6) * XS + (idx & 63)] = (n < N) ? x[(size_t)n * 64 + (idx & 63)] : 0.f;
    }
    __syncthreads();
    const int og = tid & 15;   // 16 out-groups x 8 outs
    const int ng = tid >> 4;   // 16 node-groups x 4 nodes
    float acc[8][4];
#pragma unroll
    for (int r = 0; r < 8; ++r)
#pragma unroll
        for (int n = 0; n < 4; ++n) acc[r][n] = 0.f;
    for (int k4 = 0; k4 < 16; ++k4) {
        float4 hv[4];
#pragma unroll
        for (int n = 0; n < 4; ++n) hv[n] = *(const float4*)&xs[(ng * 4 + n) * XS + k4 * 4];
#pragma unroll
        for (int j = 0; j < 4; ++j) {
            const float* wr = tW + (k4 * 4 + j) * 128 + og * 8;
            float4 w0 = *(const float4*)wr;
            float4 w1 = *(const float4*)(wr + 4);
#pragma unroll
            for (int n = 0; n < 4; ++n) {
                float hj = (&hv[n].x)[j];
                acc[0][n] += w0.x * hj; acc[1][n] += w0.y * hj;
                acc[2][n] += w0.z * hj; acc[3][n] += w0.w * hj;
                acc[4][n] += w1.x * hj; acc[5][n] += w1.y * hj;
                acc[6][n] += w1.z * hj; acc[7][n] += w1.w * hj;
            }
        }
    }
    float4 b0 = *(const float4*)&b[og * 8];
    float4 b1 = *(const float4*)&b[og * 8 + 4];
#pragma unroll
    for (int n = 0; n < 4; ++n) {
        int node = base + ng * 4 + n;
        if (node < N) {
            float4 o0 = make_float4(fmaxf(acc[0][n] + b0.x, 0.f), fmaxf(acc[1][n] + b0.y, 0.f),
                                    fmaxf(acc[2][n] + b0.z, 0.f), fmaxf(acc[3][n] + b0.w, 0.f));
            float4 o1 = make_float4(fmaxf(acc[4][n] + b1.x, 0.f), fmaxf(acc[5][n] + b1.y, 0.f),
                                    fmaxf(acc[6][n] + b1.z, 0.f), fmaxf(acc[7][n] + b1.w, 0.f));
            *(float4*)&h[(size_t)node * 128 + og * 8] = o0;
            *(float4*)&h[(size_t)node * 128 + og * 8 + 4] = o1;
        }
    }
}

// entangle circuit per node; h scaled by invS = rcp(sumexp[l])
__global__ void k_ent(const float* __restrict__ h, const float* __restrict__ rotE,
                      const float* __restrict__ pS, float* __restrict__ xq, int N) {
    int n = blockIdx.x * blockDim.x + threadIdx.x;
    if (n >= N) return;
    const float invS = __builtin_amdgcn_rcpf(pS[0]);
    float4 hv = *(const float4*)&h[(size_t)n * 128];
    float sr[16], si[16];
    init_state(sr, si);
    { float s, c; __sincosf(fast_tanh(hv.x * invS) * (0.5f * PI_HALF), &s, &c); ry_g<8>(sr, si, c, s); }
    { float s, c; __sincosf(fast_tanh(hv.y * invS) * (0.5f * PI_HALF), &s, &c); ry_g<4>(sr, si, c, s); }
    { float s, c; __sincosf(fast_tanh(hv.z * invS) * (0.5f * PI_HALF), &s, &c); ry_g<2>(sr, si, c, s); }
    { float s, c; __sincosf(fast_tanh(hv.w * invS) * (0.5f * PI_HALF), &s, &c); ry_g<1>(sr, si, c, s); }
#pragma unroll
    for (int l = 0; l < 2; ++l) {
        cnot_g<8, 4>(sr, si); cnot_g<4, 2>(sr, si); cnot_g<2, 1>(sr, si);
        const float* P = rotE + l * 32;
        rot_pre<8>(sr, si, P);
        rot_pre<4>(sr, si, P + 8);
        rot_pre<2>(sr, si, P + 16);
        rot_pre<1>(sr, si, P + 24);
        cnot_g<8, 1>(sr, si);  // CNOT(0, 3)
    }
    float z[4]; zexp_g(sr, si, z);
    *(float4*)&xq[(size_t)n * 4] = make_float4(z[0], z[1], z[2], z[3]);
}

// x_comb + q/k (c,s): 64 nodes/block, 256 thr, 8x4 register tile, tlinW[k][o]
#define HS 132
__global__ __launch_bounds__(256) void k_lin(
        const float* __restrict__ h, const float* __restrict__ xq,
        const float* __restrict__ tlinW, const float* __restrict__ linb,
        const float* __restrict__ qpW, const float* __restrict__ qpb,
        const float* __restrict__ aqW, const float* __restrict__ aqb,
        const float* __restrict__ akW, const float* __restrict__ akb,
        const float* __restrict__ pS,
        float* __restrict__ xcomb, float* __restrict__ qbuf,
        float* __restrict__ kbuf, int N) {
    __shared__ float hs[64 * HS];
    __shared__ float zS[64 * 4];
    const int base = blockIdx.x * 64;
    const int tid = threadIdx.x;
    const float invS = __builtin_amdgcn_rcpf(pS[0]);
    for (int idx = tid; idx < 64 * 128; idx += 256) {
        int n = base + (idx >> 7);
        hs[(idx >> 7) * HS + (idx & 127)] =
            (n < N) ? h[(size_t)n * 128 + (idx & 127)] * invS : 0.f;
    }
    {
        int n = base + (tid >> 2);
        zS[tid] = (n < N) ? xq[(size_t)n * 4 + (tid & 3)] : 0.f;
    }
    __syncthreads();

    const int og = tid & 15;
    const int ng = tid >> 4;
    float acc[8][4];
#pragma unroll
    for (int r = 0; r < 8; ++r)
#pragma unroll
        for (int n = 0; n < 4; ++n) acc[r][n] = 0.f;
    for (int k4 = 0; k4 < 32; ++k4) {
        float4 hv[4];
#pragma unroll
        for (int n = 0; n < 4; ++n) hv[n] = *(const float4*)&hs[(ng * 4 + n) * HS + k4 * 4];
#pragma unroll
        for (int j = 0; j < 4; ++j) {
            const float* wr = tlinW + (k4 * 4 + j) * 128 + og * 8;
            float4 w0 = *(const float4*)wr;
            float4 w1 = *(const float4*)(wr + 4);
#pragma unroll
            for (int n = 0; n < 4; ++n) {
                float hj = (&hv[n].x)[j];
                acc[0][n] += w0.x * hj; acc[1][n] += w0.y * hj;
                acc[2][n] += w0.z * hj; acc[3][n] += w0.w * hj;
                acc[4][n] += w1.x * hj; acc[5][n] += w1.y * hj;
                acc[6][n] += w1.z * hj; acc[7][n] += w1.w * hj;
            }
        }
    }

    // q/k dots: thread -> node (tid>>2), qi (tid&3); one q-dot and one k-dot each
    {
        const int nl = tid >> 2;
        const int qi = tid & 3;
        const float4* Wq4 = (const float4*)(aqW + qi * 128);
        const float4* Wk4 = (const float4*)(akW + qi * 128);
        float dq = aqb[qi], dk = akb[qi];
        for (int c4 = 0; c4 < 32; ++c4) {
            float4 hv = *(const float4*)&hs[nl * HS + c4 * 4];
            float4 wq = Wq4[c4], wk = Wk4[c4];
            dq += wq.x * hv.x + wq.y * hv.y + wq.z * hv.z + wq.w * hv.w;
            dk += wk.x * hv.x + wk.y * hv.y + wk.z * hv.z + wk.w * hv.w;
        }
        int node = base + nl;
        if (node < N) {
            float s, c;
            __sincosf(fast_tanh(dq) * (0.5f * PI_HALF), &s, &c);
            qbuf[(size_t)node * 8 + qi * 2] = c;
            qbuf[(size_t)node * 8 + qi * 2 + 1] = s;
            __sincosf(fast_tanh(dk) * (0.5f * PI_HALF), &s, &c);
            kbuf[(size_t)node * 8 + qi * 2] = c;
            kbuf[(size_t)node * 8 + qi * 2 + 1] = s;
        }
    }

    const float4 lb0 = *(const float4*)&linb[og * 8];
    const float4 lb1 = *(const float4*)&linb[og * 8 + 4];
    const float4 qb0 = *(const float4*)&qpb[og * 8];
    const float4 qb1 = *(const float4*)&qpb[og * 8 + 4];
#pragma unroll
    for (int n = 0; n < 4; ++n) {
        int node = base + ng * 4 + n;
        if (node < N) {
            float4 z = *(const float4*)&zS[(ng * 4 + n) * 4];
            float4 o0, o1;
            const float* qw = qpW + og * 32;  // 8 rows x 4
            o0.x = acc[0][n] + lb0.x + qb0.x + qw[0]*z.x + qw[1]*z.y + qw[2]*z.z + qw[3]*z.w;
            o0.y = acc[1][n] + lb0.y + qb0.y + qw[4]*z.x + qw[5]*z.y + qw[6]*z.z + qw[7]*z.w;
            o0.z = acc[2][n] + lb0.z + qb0.z + qw[8]*z.x + qw[9]*z.y + qw[10]*z.z + qw[11]*z.w;
            o0.w = acc[3][n] + lb0.w + qb0.w + qw[12]*z.x + qw[13]*z.y + qw[14]*z.z + qw[15]*z.w;
            o1.x = acc[4][n] + lb1.x + qb1.x + qw[16]*z.x + qw[17]*z.y + qw[18]*z.z + qw[19]*z.w;
            o1.y = acc[5][n] + lb1.y + qb1.y + qw[20]*z.x + qw[21]*z.y + qw[22]*z.z + qw[23]*z.w;
            o1.z = acc[6][n] + lb1.z + qb1.z + qw[24]*z.x + qw[25]*z.y + qw[26]*z.z + qw[27]*z.w;
            o1.w = acc[7][n] + lb1.w + qb1.w + qw[28]*z.x + qw[29]*z.y + qw[30]*z.z + qw[31]*z.w;
            *(float4*)&xcomb[(size_t)node * 128 + og * 8] = o0;
            *(float4*)&xcomb[(size_t)node * 128 + og * 8 + 4] = o1;
        }
    }
}

// attention circuit per slot (dst-binned order): one thread per slot, full lanes.
// writes exp(score) to escore[p]; accumulates sum of exp into sumexp_next.
__global__ void k_att(const float* __restrict__ qb, const float* __restrict__ kb,
                      const int* __restrict__ srcs, const int* __restrict__ dsts,
                      const float* __restrict__ RA, float* __restrict__ escore,
                      float* __restrict__ sumexp_next, int EP) {
    __shared__ float red[4];
    int p = blockIdx.x * blockDim.x + threadIdx.x;
    float ex = 0.f;
    if (p < EP) {
        int s_ = srcs[p], d_ = dsts[p];
        float4 qa = *(const float4*)&qb[(size_t)s_ * 8];
        float4 qc = *(const float4*)&qb[(size_t)s_ * 8 + 4];
        float4 ka = *(const float4*)&kb[(size_t)d_ * 8];
        float4 kc = *(const float4*)&kb[(size_t)d_ * 8 + 4];
        float sr[16], si[16];
        init_state(sr, si);
        ry_g<8>(sr, si, qa.x, qa.y);
        ry_g<4>(sr, si, qa.z, qa.w);
        ry_g<2>(sr, si, qc.x, qc.y);
        ry_g<1>(sr, si, qc.z, qc.w);
        had_g<8>(sr, si); had_g<4>(sr, si); had_g<2>(sr, si); had_g<1>(sr, si);
        cry_g<8, 4>(sr, si, ka.x, ka.y);
        cry_g<4, 2>(sr, si, ka.z, ka.w);
        cry_g<2, 1>(sr, si, kc.x, kc.y);
        cry_g<1, 8>(sr, si, kc.z, kc.w);
        rot_pre<8>(sr, si, RA);
        rot_pre<4>(sr, si, RA + 8);
        rot_pre<2>(sr, si, RA + 16);
        rot_pre<1>(sr, si, RA + 24);
        float z[4]; zexp_g(sr, si, z);
        float sc = 0.25f * (z[0] + z[1] + z[2] + z[3]);
        ex = __expf(sc);
        escore[p] = ex;
    }
    float w = ex;
#pragma unroll
    for (int d = 32; d > 0; d >>= 1) w += __shfl_down(w, d, 64);
    if ((threadIdx.x & 63) == 0) red[threadIdx.x >> 6] = w;
    __syncthreads();
    if (threadIdx.x == 0)
        atomicAdd(sumexp_next, red[0] + red[1] + red[2] + red[3]);
}

// one block per dst: g[dst,:] = relu( sum_slot escore[slot]*xcomb[srcs[slot],:] )
// (normalization by sumexp deferred to consumers)
__global__ void k_gather(const float* __restrict__ xcomb, const int* __restrict__ srcs,
                         const float* __restrict__ escore, const int* __restrict__ off,
                         const int* __restrict__ cnt, float* __restrict__ g) {
    __shared__ int sS[128];
    __shared__ float wS[128];
    const int b = blockIdx.x;
    const int tid = threadIdx.x;  // 128
    const int start = off[b];
    const int num = cnt[b];
    float acc = 0.f;
    for (int base = 0; base < num; base += 128) {
        int m = min(128, num - base);
        if (tid < m) {
            sS[tid] = srcs[start + base + tid];
            wS[tid] = escore[start + base + tid];
        }
        __syncthreads();
#pragma unroll 4
        for (int i = 0; i < m; ++i)
            acc += wS[i] * xcomb[(size_t)sS[i] * 128 + tid];
        __syncthreads();
    }
    g[(size_t)b * 128 + tid] = fmaxf(acc, 0.f);
}

// pq (c,s) pairs; h scaled by invS; 32 nodes/block, 128 thr
__global__ void k_pq(const float* __restrict__ h, const float* __restrict__ piW,
                     const float* __restrict__ pib, const float* __restrict__ pS,
                     float* __restrict__ pq8, int N) {
    __shared__ float hs[32 * HS];
    const int base = blockIdx.x * 32;
    const int tid = threadIdx.x;  // 128
    const float invS = __builtin_amdgcn_rcpf(pS[0]);
    for (int idx = tid; idx < 32 * 128; idx += 128) {
        int n = base + (idx >> 7);
        hs[(idx >> 7) * HS + (idx & 127)] =
            (n < N) ? h[(size_t)n * 128 + (idx & 127)] * invS : 0.f;
    }
    __syncthreads();
    const int nl = tid >> 2;
    const int i  = tid & 3;
    float dot = pib[i];
    const float4* w4 = (const float4*)(piW + i * 128);
    for (int c4 = 0; c4 < 32; ++c4) {
        float4 w = w4[c4];
        float4 hv = *(const float4*)&hs[nl * HS + c4 * 4];
        dot += w.x * hv.x + w.y * hv.y + w.z * hv.z + w.w * hv.w;
    }
    int node = base + nl;
    if (node < N) {
        float s, c; __sincosf(fast_tanh(dot) * (0.5f * PI_HALF), &s, &c);
        pq8[(size_t)node * 8 + i * 2]     = c;
        pq8[(size_t)node * 8 + i * 2 + 1] = s;
    }
}

// path circuit per node + epilogue out = M@z + v (coalesced via LDS staging)
__global__ void k_pathc(const float* __restrict__ pq8, const float* __restrict__ RP,
                        const float* __restrict__ M, const float* __restrict__ v,
                        float* __restrict__ out, int N) {
    __shared__ float zS[256 * 4];
    __shared__ float MS[128];
    __shared__ float vS[32];
    const int tid = threadIdx.x;  // 256
    if (tid < 128) MS[tid] = M[tid];
    else if (tid < 160) vS[tid - 128] = v[tid - 128];
    __syncthreads();
    const int base = blockIdx.x * 256;
    const int n = base + tid;
    if (n < N) {
        float4 pa = *(const float4*)&pq8[(size_t)n * 8];
        float4 pc = *(const float4*)&pq8[(size_t)n * 8 + 4];
        float sr[16], si[16];
        init_state(sr, si);
        had_g<8>(sr, si); had_g<4>(sr, si); had_g<2>(sr, si); had_g<1>(sr, si);
        ry_g<8>(sr, si, pa.x, pa.y);
        ry_g<4>(sr, si, pa.z, pa.w);
        ry_g<2>(sr, si, pc.x, pc.y);
        ry_g<1>(sr, si, pc.z, pc.w);
#pragma unroll
        for (int l = 0; l < 3; ++l) {
            const float* P = RP + l * 32;
            rot_pre<8>(sr, si, P);
            rot_pre<4>(sr, si, P + 8);
            rot_pre<2>(sr, si, P + 16);
            rot_pre<1>(sr, si, P + 24);
            cnot_g<8, 4>(sr, si); cnot_g<4, 2>(sr, si); cnot_g<2, 1>(sr, si);
        }
        float z[4]; zexp_g(sr, si, z);
        zS[tid * 4 + 0] = z[0]; zS[tid * 4 + 1] = z[1];
        zS[tid * 4 + 2] = z[2]; zS[tid * 4 + 3] = z[3];
    }
    __syncthreads();
#pragma unroll
    for (int k = 0; k < 32; ++k) {
        int flat = k * 256 + tid;
        int nl = flat >> 5;
        int o = flat & 31;
        int node = base + nl;
        if (node < N) {
            out[(size_t)node * 32 + o] = vS[o]
                + MS[o * 4 + 0] * zS[nl * 4 + 0] + MS[o * 4 + 1] * zS[nl * 4 + 1]
                + MS[o * 4 + 2] * zS[nl * 4 + 2] + MS[o * 4 + 3] * zS[nl * 4 + 3];
        }
    }
}

// ---------------- launch ----------------------------------------------------

extern "C" void kernel_launch(void* const* d_in, const int* in_sizes, int n_in,
                              void* d_out, int out_size, void* d_ws, size_t ws_size,
                              hipStream_t stream) {
    const float* x     = (const float*)d_in[0];
    const float* W_in  = (const float*)d_in[1];
    const float* b_in  = (const float*)d_in[2];
    const float* linW  = (const float*)d_in[3];
    const float* linb  = (const float*)d_in[4];
    const float* qpW   = (const float*)d_in[5];
    const float* qpb   = (const float*)d_in[6];
    const float* entp  = (const float*)d_in[7];
    const float* aqW   = (const float*)d_in[8];
    const float* aqb   = (const float*)d_in[9];
    const float* akW   = (const float*)d_in[10];
    const float* akb   = (const float*)d_in[11];
    const float* attqp = (const float*)d_in[12];
    const float* pparm = (const float*)d_in[13];
    const float* piW   = (const float*)d_in[14];
    const float* pib   = (const float*)d_in[15];
    const float* poW   = (const float*)d_in[16];
    const float* pob   = (const float*)d_in[17];
    const float* outW  = (const float*)d_in[18];
    const float* outb  = (const float*)d_in[19];
    const int*   ei    = (const int*)d_in[20];

    const int N  = in_sizes[0] / 64;   // 20000
    const int E  = in_sizes[20] / 2;   // 300000
    const int EP = E + N;              // self-loops appended

    float* ws     = (float*)d_ws;
    float* h      = ws;
    float* xcomb  = h      + (size_t)N * 128;
    float* xq     = xcomb  + (size_t)N * 128;
    float* qbuf   = xq     + (size_t)N * 4;
    float* kbuf   = qbuf   + (size_t)N * 8;
    float* pq8    = kbuf   + (size_t)N * 8;
    float* escore = pq8    + (size_t)N * 8;
    float* tWin   = escore + EP;
    float* tl0    = tWin   + 64 * 128;
    float* tl1    = tl0    + 128 * 128;
    float* rotbuf = tl1    + 128 * 128;
    float* Mm     = rotbuf + 36 * 8;
    float* vv     = Mm + 128;
    int*   cnt    = (int*)(vv + 32);
    float* sumexp = (float*)(cnt + N);   // 3 slots: [0]=1.0, [1]=layer0, [2]=layer1
    int*   off    = (int*)(sumexp + 4);
    int*   cur    = off + N;
    int*   srcs   = cur + N;
    int*   dsts   = srcs + EP;

    const float* rotE = rotbuf;          // 16 matrices
    const float* rotA = rotbuf + 128;    // 8 matrices
    const float* rotP = rotbuf + 192;    // 12 matrices

    const int nb64 = (N + 63) / 64;
    const int ebl  = (EP + 255) / 256;

    hipMemsetAsync(cnt, 0, (size_t)(N + 4) * sizeof(int), stream);
    k_hist<<<ebl, 256, 0, stream>>>(ei, cnt, E, EP);
    k_scan<<<1, 1024, 0, stream>>>(cnt, off, cur, N);
    k_fill<<<ebl, 256, 0, stream>>>(ei, cur, srcs, dsts, E, EP);
    k_setup<<<1, 256, 0, stream>>>(entp, attqp, pparm, outW, outb, poW, pob,
                                   rotbuf, Mm, vv, sumexp);
    k_tr<<<96, 256, 0, stream>>>(W_in, linW, linW + 128 * 128, tWin, tl0, tl1);
    k_in<<<nb64, 256, 0, stream>>>(x, tWin, b_in, h, N);

    for (int l = 0; l < 2; ++l) {
        const float* tl = (l == 0) ? tl0 : tl1;
        k_ent<<<(N + 255) / 256, 256, 0, stream>>>(h, rotE + l * 64, sumexp + l, xq, N);
        k_lin<<<nb64, 256, 0, stream>>>(h, xq, tl,
            linb + l * 128,
            qpW + (size_t)l * 128 * 4, qpb + l * 128,
            aqW + (size_t)l * 4 * 128, aqb + l * 4,
            akW + (size_t)l * 4 * 128, akb + l * 4,
            sumexp + l, xcomb, qbuf, kbuf, N);
        k_att<<<ebl, 256, 0, stream>>>(qbuf, kbuf, srcs, dsts, rotA + l * 32,
                                       escore, sumexp + l + 1, EP);
        k_gather<<<N, 128, 0, stream>>>(xcomb, srcs, escore, off, cnt, h);
    }

    k_pq<<<(N + 31) / 32, 128, 0, stream>>>(h, piW, pib, sumexp + 2, pq8, N);
    k_pathc<<<(N + 255) / 256, 256, 0, stream>>>(pq8, rotP, Mm, vv, (float*)d_out, N);
}

// Round 8
// 412.626 us; speedup vs baseline: 2.0615x; 1.0187x over previous
//
#include <hip/hip_runtime.h>
#include <math.h>

#define PI_HALF 1.57079632679489662f

__device__ __forceinline__ float fast_tanh(float x) {
    float e = __expf(2.f * x);
    return 1.f - 2.f * __builtin_amdgcn_rcpf(e + 1.f);
}

// ---------------- 4-qubit state helpers (compile-time masks -> registers) ----
// wire w (0..3) maps to amplitude-index bit (3-w), i.e. mask = 8 >> w.

__device__ __forceinline__ void init_state(float sr[16], float si[16]) {
#pragma unroll
    for (int i = 0; i < 16; ++i) { sr[i] = 0.f; si[i] = 0.f; }
    sr[0] = 1.f;
}

template<int M>
__device__ __forceinline__ void ry_g(float sr[16], float si[16], float c, float s) {
#pragma unroll
    for (int i = 0; i < 16; ++i) {
        if (i & M) continue;
        const int j = i | M;
        float ar = sr[i], ai = si[i], br = sr[j], bi = si[j];
        sr[i] = c * ar - s * br;  si[i] = c * ai - s * bi;
        sr[j] = s * ar + c * br;  si[j] = s * ai + c * bi;
    }
}

template<int M>
__device__ __forceinline__ void had_g(float sr[16], float si[16]) {
    const float r = 0.70710678118654752f;
#pragma unroll
    for (int i = 0; i < 16; ++i) {
        if (i & M) continue;
        const int j = i | M;
        float ar = sr[i], ai = si[i], br = sr[j], bi = si[j];
        sr[i] = (ar + br) * r;  si[i] = (ai + bi) * r;
        sr[j] = (ar - br) * r;  si[j] = (ai - bi) * r;
    }
}

template<int MC, int MT>
__device__ __forceinline__ void cnot_g(float sr[16], float si[16]) {
#pragma unroll
    for (int i = 0; i < 16; ++i) {
        if (!(i & MC) || (i & MT)) continue;
        const int j = i | MT;
        float tr = sr[i], ti = si[i];
        sr[i] = sr[j]; si[i] = si[j];
        sr[j] = tr;    si[j] = ti;
    }
}

template<int MC, int MT>
__device__ __forceinline__ void cry_g(float sr[16], float si[16], float c, float s) {
#pragma unroll
    for (int i = 0; i < 16; ++i) {
        if (!(i & MC) || (i & MT)) continue;
        const int j = i | MT;
        float ar = sr[i], ai = si[i], br = sr[j], bi = si[j];
        sr[i] = c * ar - s * br;  si[i] = c * ai - s * bi;
        sr[j] = s * ar + c * br;  si[j] = s * ai + c * bi;
    }
}

template<int M>
__device__ __forceinline__ void rot_pre(float sr[16], float si[16], const float* __restrict__ u) {
    const float u00r = u[0], u00i = u[1], u01r = u[2], u01i = u[3];
    const float u10r = u[4], u10i = u[5], u11r = u[6], u11i = u[7];
#pragma unroll
    for (int i = 0; i < 16; ++i) {
        if (i & M) continue;
        const int j = i | M;
        float ar = sr[i], ai = si[i], br = sr[j], bi = si[j];
        sr[i] = u00r * ar - u00i * ai + u01r * br - u01i * bi;
        si[i] = u00r * ai + u00i * ar + u01r * bi + u01i * br;
        sr[j] = u10r * ar - u10i * ai + u11r * br - u11i * bi;
        si[j] = u10r * ai + u10i * ar + u11r * bi + u11i * br;
    }
}

__device__ __forceinline__ void zexp_g(const float sr[16], const float si[16], float z[4]) {
    float p[16];
#pragma unroll
    for (int i = 0; i < 16; ++i) p[i] = sr[i] * sr[i] + si[i] * si[i];
    z[0] = z[1] = z[2] = z[3] = 0.f;
#pragma unroll
    for (int i = 0; i < 16; ++i) {
        z[0] += (i & 8) ? -p[i] : p[i];
        z[1] += (i & 4) ? -p[i] : p[i];
        z[2] += (i & 2) ? -p[i] : p[i];
        z[3] += (i & 1) ? -p[i] : p[i];
    }
}

// ---------------- setup: rot matrices + fused output matrix + sumexp[0]=1 ----
__global__ void k_setup(const float* __restrict__ entp, const float* __restrict__ attqp,
                        const float* __restrict__ pparm,
                        const float* __restrict__ outW, const float* __restrict__ outb,
                        const float* __restrict__ poW, const float* __restrict__ pob,
                        float* __restrict__ rotbuf, float* __restrict__ M,
                        float* __restrict__ v, float* __restrict__ sumexp) {
    const int t = threadIdx.x;
    if (t < 36) {
        const float* p;
        if (t < 16)      p = entp  + t * 3;
        else if (t < 24) p = attqp + (t - 16) * 3;
        else             p = pparm + (t - 24) * 3;
        float phi = p[0], theta = p[1], omega = p[2];
        float st, ct; sincosf(0.5f * theta, &st, &ct);
        float sp, cp; sincosf(0.5f * (phi + omega), &sp, &cp);
        float sm, cm; sincosf(0.5f * (phi - omega), &sm, &cm);
        float* u = rotbuf + t * 8;
        u[0] =  ct * cp;  u[1] = -ct * sp;
        u[2] = -st * cm;  u[3] = -st * sm;
        u[4] =  st * cm;  u[5] = -st * sm;
        u[6] =  ct * cp;  u[7] =  ct * sp;
    } else if (t >= 64 && t < 192) {
        int t2 = t - 64;
        int o = t2 >> 2, i = t2 & 3;
        float acc = 0.f;
        for (int j = 0; j < 128; ++j) acc += outW[o * 128 + j] * poW[j * 4 + i];
        M[t2] = acc;
    } else if (t >= 192 && t < 224) {
        int o = t - 192;
        float acc = outb[o];
        for (int j = 0; j < 128; ++j) acc += outW[o * 128 + j] * pob[j];
        v[o] = acc;
    } else if (t == 255) {
        sumexp[0] = 1.0f;  // layer-0 h is unnormalized (scale 1)
    }
}

// transpose weights: tWin[64][128] <- Win[128][64]; tl{0,1}[128][128] <- linW[l][o][k]
__global__ void k_tr(const float* __restrict__ Win, const float* __restrict__ l0,
                     const float* __restrict__ l1, float* __restrict__ tWin,
                     float* __restrict__ tl0, float* __restrict__ tl1) {
    int i = blockIdx.x * 256 + threadIdx.x;
    if (i < 64 * 128) {
        int k = i >> 7, o = i & 127;
        tWin[i] = Win[o * 64 + k];
    }
    int j = i - 64 * 128;
    if (j >= 0 && j < 128 * 128) {
        int k = j >> 7, o = j & 127;
        tl0[j] = l0[o * 128 + k];
        tl1[j] = l1[o * 128 + k];
    }
}

// ---------------- dst binning (edge_index layer-invariant: built once) -------

__global__ void k_hist(const int* __restrict__ ei, int* __restrict__ cnt, int E, int EP) {
    int e = blockIdx.x * blockDim.x + threadIdx.x;
    if (e >= EP) return;
    int d_ = (e < E) ? ei[E + e] : e - E;
    atomicAdd(&cnt[d_], 1);
}

__global__ void k_scan(const int* __restrict__ cnt, int* __restrict__ off,
                       int* __restrict__ cur, int N) {
    __shared__ int tot[1024];
    const int t = threadIdx.x;
    const int chunk = (N + 1023) >> 10;
    const int s0 = t * chunk;
    const int s1 = min(s0 + chunk, N);
    int sum = 0;
    for (int i = s0; i < s1; ++i) sum += cnt[i];
    tot[t] = sum;
    __syncthreads();
    for (int d = 1; d < 1024; d <<= 1) {
        int v = (t >= d) ? tot[t - d] : 0;
        __syncthreads();
        tot[t] += v;
        __syncthreads();
    }
    int run = (t == 0) ? 0 : tot[t - 1];
    for (int i = s0; i < s1; ++i) {
        off[i] = run; cur[i] = run;
        run += cnt[i];
    }
}

__global__ void k_fill(const int* __restrict__ ei, int* __restrict__ cur,
                       int* __restrict__ srcs, int* __restrict__ dsts, int E, int EP) {
    int e = blockIdx.x * blockDim.x + threadIdx.x;
    if (e >= EP) return;
    int s_, d_;
    if (e < E) { s_ = ei[e]; d_ = ei[E + e]; } else { s_ = d_ = e - E; }
    int pos = atomicAdd(&cur[d_], 1);
    srcs[pos] = s_;
    dsts[pos] = d_;
}

// ---------------- GEMM-style node kernels (8-out x 2-node register tiles) ----
// 32 nodes/block -> 625 blocks -> ~10 waves/CU (vs 313 blocks @9% occ in R7)

// h = relu(x @ W_in^T + b_in); tW[k][o] coalesced
#define XS 68
__global__ __launch_bounds__(256) void k_in(
        const float* __restrict__ x, const float* __restrict__ tW,
        const float* __restrict__ b, float* __restrict__ h, int N) {
    __shared__ float xs[32 * XS];
    const int base = blockIdx.x * 32;
    const int tid = threadIdx.x;
    for (int idx = tid; idx < 32 * 64; idx += 256) {
        int n = base + (idx >> 6);
        xs[(idx >> 6) * XS + (idx & 63)] = (n < N) ? x[(size_t)n * 64 + (idx & 63)] : 0.f;
    }
    __syncthreads();
    const int og = tid & 15;   // 16 out-groups x 8 outs
    const int ng = tid >> 4;   // 16 node-groups x 2 nodes
    float acc[8][2];
#pragma unroll
    for (int r = 0; r < 8; ++r) { acc[r][0] = 0.f; acc[r][1] = 0.f; }
    for (int k4 = 0; k4 < 16; ++k4) {
        float4 hv0 = *(const float4*)&xs[(ng * 2) * XS + k4 * 4];
        float4 hv1 = *(const float4*)&xs[(ng * 2 + 1) * XS + k4 * 4];
#pragma unroll
        for (int j = 0; j < 4; ++j) {
            const float* wr = tW + (k4 * 4 + j) * 128 + og * 8;
            float4 w0 = *(const float4*)wr;
            float4 w1 = *(const float4*)(wr + 4);
            float h0 = (&hv0.x)[j], h1 = (&hv1.x)[j];
            acc[0][0] += w0.x * h0; acc[1][0] += w0.y * h0;
            acc[2][0] += w0.z * h0; acc[3][0] += w0.w * h0;
            acc[4][0] += w1.x * h0; acc[5][0] += w1.y * h0;
            acc[6][0] += w1.z * h0; acc[7][0] += w1.w * h0;
            acc[0][1] += w0.x * h1; acc[1][1] += w0.y * h1;
            acc[2][1] += w0.z * h1; acc[3][1] += w0.w * h1;
            acc[4][1] += w1.x * h1; acc[5][1] += w1.y * h1;
            acc[6][1] += w1.z * h1; acc[7][1] += w1.w * h1;
        }
    }
    float4 b0 = *(const float4*)&b[og * 8];
    float4 b1 = *(const float4*)&b[og * 8 + 4];
#pragma unroll
    for (int n = 0; n < 2; ++n) {
        int node = base + ng * 2 + n;
        if (node < N) {
            float4 o0 = make_float4(fmaxf(acc[0][n] + b0.x, 0.f), fmaxf(acc[1][n] + b0.y, 0.f),
                                    fmaxf(acc[2][n] + b0.z, 0.f), fmaxf(acc[3][n] + b0.w, 0.f));
            float4 o1 = make_float4(fmaxf(acc[4][n] + b1.x, 0.f), fmaxf(acc[5][n] + b1.y, 0.f),
                                    fmaxf(acc[6][n] + b1.z, 0.f), fmaxf(acc[7][n] + b1.w, 0.f));
            *(float4*)&h[(size_t)node * 128 + og * 8] = o0;
            *(float4*)&h[(size_t)node * 128 + og * 8 + 4] = o1;
        }
    }
}

// entangle circuit per node; h scaled by invS = rcp(sumexp[l])
__global__ void k_ent(const float* __restrict__ h, const float* __restrict__ rotE,
                      const float* __restrict__ pS, float* __restrict__ xq, int N) {
    int n = blockIdx.x * blockDim.x + threadIdx.x;
    if (n >= N) return;
    const float invS = __builtin_amdgcn_rcpf(pS[0]);
    float4 hv = *(const float4*)&h[(size_t)n * 128];
    float sr[16], si[16];
    init_state(sr, si);
    { float s, c; __sincosf(fast_tanh(hv.x * invS) * (0.5f * PI_HALF), &s, &c); ry_g<8>(sr, si, c, s); }
    { float s, c; __sincosf(fast_tanh(hv.y * invS) * (0.5f * PI_HALF), &s, &c); ry_g<4>(sr, si, c, s); }
    { float s, c; __sincosf(fast_tanh(hv.z * invS) * (0.5f * PI_HALF), &s, &c); ry_g<2>(sr, si, c, s); }
    { float s, c; __sincosf(fast_tanh(hv.w * invS) * (0.5f * PI_HALF), &s, &c); ry_g<1>(sr, si, c, s); }
#pragma unroll
    for (int l = 0; l < 2; ++l) {
        cnot_g<8, 4>(sr, si); cnot_g<4, 2>(sr, si); cnot_g<2, 1>(sr, si);
        const float* P = rotE + l * 32;
        rot_pre<8>(sr, si, P);
        rot_pre<4>(sr, si, P + 8);
        rot_pre<2>(sr, si, P + 16);
        rot_pre<1>(sr, si, P + 24);
        cnot_g<8, 1>(sr, si);  // CNOT(0, 3)
    }
    float z[4]; zexp_g(sr, si, z);
    *(float4*)&xq[(size_t)n * 4] = make_float4(z[0], z[1], z[2], z[3]);
}

// x_comb + q/k (c,s): 32 nodes/block, 256 thr, 8x2 register tile, tlinW[k][o]
#define HS 132
__global__ __launch_bounds__(256) void k_lin(
        const float* __restrict__ h, const float* __restrict__ xq,
        const float* __restrict__ tlinW, const float* __restrict__ linb,
        const float* __restrict__ qpW, const float* __restrict__ qpb,
        const float* __restrict__ aqW, const float* __restrict__ aqb,
        const float* __restrict__ akW, const float* __restrict__ akb,
        const float* __restrict__ pS,
        float* __restrict__ xcomb, float* __restrict__ qbuf,
        float* __restrict__ kbuf, int N) {
    __shared__ float hs[32 * HS];
    __shared__ float zS[32 * 4];
    const int base = blockIdx.x * 32;
    const int tid = threadIdx.x;
    const float invS = __builtin_amdgcn_rcpf(pS[0]);
    for (int idx = tid; idx < 32 * 128; idx += 256) {
        int n = base + (idx >> 7);
        hs[(idx >> 7) * HS + (idx & 127)] =
            (n < N) ? h[(size_t)n * 128 + (idx & 127)] * invS : 0.f;
    }
    if (tid < 128) {
        int n = base + (tid >> 2);
        zS[tid] = (n < N) ? xq[(size_t)n * 4 + (tid & 3)] : 0.f;
    }
    __syncthreads();

    const int og = tid & 15;   // 16 out-groups x 8 outs
    const int ng = tid >> 4;   // 16 node-groups x 2 nodes
    float acc[8][2];
#pragma unroll
    for (int r = 0; r < 8; ++r) { acc[r][0] = 0.f; acc[r][1] = 0.f; }
    for (int k4 = 0; k4 < 32; ++k4) {
        float4 hv0 = *(const float4*)&hs[(ng * 2) * HS + k4 * 4];
        float4 hv1 = *(const float4*)&hs[(ng * 2 + 1) * HS + k4 * 4];
#pragma unroll
        for (int j = 0; j < 4; ++j) {
            const float* wr = tlinW + (k4 * 4 + j) * 128 + og * 8;
            float4 w0 = *(const float4*)wr;
            float4 w1 = *(const float4*)(wr + 4);
            float h0 = (&hv0.x)[j], h1 = (&hv1.x)[j];
            acc[0][0] += w0.x * h0; acc[1][0] += w0.y * h0;
            acc[2][0] += w0.z * h0; acc[3][0] += w0.w * h0;
            acc[4][0] += w1.x * h0; acc[5][0] += w1.y * h0;
            acc[6][0] += w1.z * h0; acc[7][0] += w1.w * h0;
            acc[0][1] += w0.x * h1; acc[1][1] += w0.y * h1;
            acc[2][1] += w0.z * h1; acc[3][1] += w0.w * h1;
            acc[4][1] += w1.x * h1; acc[5][1] += w1.y * h1;
            acc[6][1] += w1.z * h1; acc[7][1] += w1.w * h1;
        }
    }

    // q/k dots: 256 threads = 32 nodes x (4 q + 4 k); row-bank map 4r%32 -> no conflicts
    {
        const int nl = tid >> 3;
        const int which = tid & 7;
        const int qi = which & 3;
        const float4* Wp4 = (const float4*)(((which < 4) ? aqW : akW) + qi * 128);
        float dot = (which < 4) ? aqb[qi] : akb[qi];
        for (int c4 = 0; c4 < 32; ++c4) {
            float4 w = Wp4[c4];
            float4 hv = *(const float4*)&hs[nl * HS + c4 * 4];
            dot += w.x * hv.x + w.y * hv.y + w.z * hv.z + w.w * hv.w;
        }
        int node = base + nl;
        if (node < N) {
            float s, c; __sincosf(fast_tanh(dot) * (0.5f * PI_HALF), &s, &c);
            float* dst = ((which < 4) ? qbuf : kbuf) + (size_t)node * 8 + qi * 2;
            dst[0] = c; dst[1] = s;
        }
    }

    const float4 lb0 = *(const float4*)&linb[og * 8];
    const float4 lb1 = *(const float4*)&linb[og * 8 + 4];
    const float4 qb0 = *(const float4*)&qpb[og * 8];
    const float4 qb1 = *(const float4*)&qpb[og * 8 + 4];
#pragma unroll
    for (int n = 0; n < 2; ++n) {
        int node = base + ng * 2 + n;
        if (node < N) {
            float4 z = *(const float4*)&zS[(ng * 2 + n) * 4];
            float4 o0, o1;
            const float* qw = qpW + og * 32;  // 8 rows x 4
            o0.x = acc[0][n] + lb0.x + qb0.x + qw[0]*z.x + qw[1]*z.y + qw[2]*z.z + qw[3]*z.w;
            o0.y = acc[1][n] + lb0.y + qb0.y + qw[4]*z.x + qw[5]*z.y + qw[6]*z.z + qw[7]*z.w;
            o0.z = acc[2][n] + lb0.z + qb0.z + qw[8]*z.x + qw[9]*z.y + qw[10]*z.z + qw[11]*z.w;
            o0.w = acc[3][n] + lb0.w + qb0.w + qw[12]*z.x + qw[13]*z.y + qw[14]*z.z + qw[15]*z.w;
            o1.x = acc[4][n] + lb1.x + qb1.x + qw[16]*z.x + qw[17]*z.y + qw[18]*z.z + qw[19]*z.w;
            o1.y = acc[5][n] + lb1.y + qb1.y + qw[20]*z.x + qw[21]*z.y + qw[22]*z.z + qw[23]*z.w;
            o1.z = acc[6][n] + lb1.z + qb1.z + qw[24]*z.x + qw[25]*z.y + qw[26]*z.z + qw[27]*z.w;
            o1.w = acc[7][n] + lb1.w + qb1.w + qw[28]*z.x + qw[29]*z.y + qw[30]*z.z + qw[31]*z.w;
            *(float4*)&xcomb[(size_t)node * 128 + og * 8] = o0;
            *(float4*)&xcomb[(size_t)node * 128 + og * 8 + 4] = o1;
        }
    }
}

// attention circuit per slot (dst-binned order): one thread per slot, full lanes.
__global__ void k_att(const float* __restrict__ qb, const float* __restrict__ kb,
                      const int* __restrict__ srcs, const int* __restrict__ dsts,
                      const float* __restrict__ RA, float* __restrict__ escore,
                      float* __restrict__ sumexp_next, int EP) {
    __shared__ float red[4];
    int p = blockIdx.x * blockDim.x + threadIdx.x;
    float ex = 0.f;
    if (p < EP) {
        int s_ = srcs[p], d_ = dsts[p];
        float4 qa = *(const float4*)&qb[(size_t)s_ * 8];
        float4 qc = *(const float4*)&qb[(size_t)s_ * 8 + 4];
        float4 ka = *(const float4*)&kb[(size_t)d_ * 8];
        float4 kc = *(const float4*)&kb[(size_t)d_ * 8 + 4];
        float sr[16], si[16];
        init_state(sr, si);
        ry_g<8>(sr, si, qa.x, qa.y);
        ry_g<4>(sr, si, qa.z, qa.w);
        ry_g<2>(sr, si, qc.x, qc.y);
        ry_g<1>(sr, si, qc.z, qc.w);
        had_g<8>(sr, si); had_g<4>(sr, si); had_g<2>(sr, si); had_g<1>(sr, si);
        cry_g<8, 4>(sr, si, ka.x, ka.y);
        cry_g<4, 2>(sr, si, ka.z, ka.w);
        cry_g<2, 1>(sr, si, kc.x, kc.y);
        cry_g<1, 8>(sr, si, kc.z, kc.w);
        rot_pre<8>(sr, si, RA);
        rot_pre<4>(sr, si, RA + 8);
        rot_pre<2>(sr, si, RA + 16);
        rot_pre<1>(sr, si, RA + 24);
        float z[4]; zexp_g(sr, si, z);
        float sc = 0.25f * (z[0] + z[1] + z[2] + z[3]);
        ex = __expf(sc);
        escore[p] = ex;
    }
    float w = ex;
#pragma unroll
    for (int d = 32; d > 0; d >>= 1) w += __shfl_down(w, d, 64);
    if ((threadIdx.x & 63) == 0) red[threadIdx.x >> 6] = w;
    __syncthreads();
    if (threadIdx.x == 0)
        atomicAdd(sumexp_next, red[0] + red[1] + red[2] + red[3]);
}

// one block per dst: g[dst,:] = relu( sum_slot escore[slot]*xcomb[srcs[slot],:] )
// (normalization by sumexp deferred to consumers)
__global__ void k_gather(const float* __restrict__ xcomb, const int* __restrict__ srcs,
                         const float* __restrict__ escore, const int* __restrict__ off,
                         const int* __restrict__ cnt, float* __restrict__ g) {
    __shared__ int sS[128];
    __shared__ float wS[128];
    const int b = blockIdx.x;
    const int tid = threadIdx.x;  // 128
    const int start = off[b];
    const int num = cnt[b];
    float acc = 0.f;
    for (int base = 0; base < num; base += 128) {
        int m = min(128, num - base);
        if (tid < m) {
            sS[tid] = srcs[start + base + tid];
            wS[tid] = escore[start + base + tid];
        }
        __syncthreads();
#pragma unroll 4
        for (int i = 0; i < m; ++i)
            acc += wS[i] * xcomb[(size_t)sS[i] * 128 + tid];
        __syncthreads();
    }
    g[(size_t)b * 128 + tid] = fmaxf(acc, 0.f);
}

// pq (c,s) pairs; h scaled by invS; 32 nodes/block, 128 thr
__global__ void k_pq(const float* __restrict__ h, const float* __restrict__ piW,
                     const float* __restrict__ pib, const float* __restrict__ pS,
                     float* __restrict__ pq8, int N) {
    __shared__ float hs[32 * HS];
    const int base = blockIdx.x * 32;
    const int tid = threadIdx.x;  // 128
    const float invS = __builtin_amdgcn_rcpf(pS[0]);
    for (int idx = tid; idx < 32 * 128; idx += 128) {
        int n = base + (idx >> 7);
        hs[(idx >> 7) * HS + (idx & 127)] =
            (n < N) ? h[(size_t)n * 128 + (idx & 127)] * invS : 0.f;
    }
    __syncthreads();
    const int nl = tid >> 2;
    const int i  = tid & 3;
    float dot = pib[i];
    const float4* w4 = (const float4*)(piW + i * 128);
    for (int c4 = 0; c4 < 32; ++c4) {
        float4 w = w4[c4];
        float4 hv = *(const float4*)&hs[nl * HS + c4 * 4];
        dot += w.x * hv.x + w.y * hv.y + w.z * hv.z + w.w * hv.w;
    }
    int node = base + nl;
    if (node < N) {
        float s, c; __sincosf(fast_tanh(dot) * (0.5f * PI_HALF), &s, &c);
        pq8[(size_t)node * 8 + i * 2]     = c;
        pq8[(size_t)node * 8 + i * 2 + 1] = s;
    }
}

// path circuit per node + epilogue out = M@z + v (coalesced via LDS staging)
__global__ void k_pathc(const float* __restrict__ pq8, const float* __restrict__ RP,
                        const float* __restrict__ M, const float* __restrict__ v,
                        float* __restrict__ out, int N) {
    __shared__ float zS[256 * 4];
    __shared__ float MS[128];
    __shared__ float vS[32];
    const int tid = threadIdx.x;  // 256
    if (tid < 128) MS[tid] = M[tid];
    else if (tid < 160) vS[tid - 128] = v[tid - 128];
    __syncthreads();
    const int base = blockIdx.x * 256;
    const int n = base + tid;
    if (n < N) {
        float4 pa = *(const float4*)&pq8[(size_t)n * 8];
        float4 pc = *(const float4*)&pq8[(size_t)n * 8 + 4];
        float sr[16], si[16];
        init_state(sr, si);
        had_g<8>(sr, si); had_g<4>(sr, si); had_g<2>(sr, si); had_g<1>(sr, si);
        ry_g<8>(sr, si, pa.x, pa.y);
        ry_g<4>(sr, si, pa.z, pa.w);
        ry_g<2>(sr, si, pc.x, pc.y);
        ry_g<1>(sr, si, pc.z, pc.w);
#pragma unroll
        for (int l = 0; l < 3; ++l) {
            const float* P = RP + l * 32;
            rot_pre<8>(sr, si, P);
            rot_pre<4>(sr, si, P + 8);
            rot_pre<2>(sr, si, P + 16);
            rot_pre<1>(sr, si, P + 24);
            cnot_g<8, 4>(sr, si); cnot_g<4, 2>(sr, si); cnot_g<2, 1>(sr, si);
        }
        float z[4]; zexp_g(sr, si, z);
        zS[tid * 4 + 0] = z[0]; zS[tid * 4 + 1] = z[1];
        zS[tid * 4 + 2] = z[2]; zS[tid * 4 + 3] = z[3];
    }
    __syncthreads();
#pragma unroll
    for (int k = 0; k < 32; ++k) {
        int flat = k * 256 + tid;
        int nl = flat >> 5;
        int o = flat & 31;
        int node = base + nl;
        if (node < N) {
            out[(size_t)node * 32 + o] = vS[o]
                + MS[o * 4 + 0] * zS[nl * 4 + 0] + MS[o * 4 + 1] * zS[nl * 4 + 1]
                + MS[o * 4 + 2] * zS[nl * 4 + 2] + MS[o * 4 + 3] * zS[nl * 4 + 3];
        }
    }
}

// ---------------- launch ----------------------------------------------------

extern "C" void kernel_launch(void* const* d_in, const int* in_sizes, int n_in,
                              void* d_out, int out_size, void* d_ws, size_t ws_size,
                              hipStream_t stream) {
    const float* x     = (const float*)d_in[0];
    const float* W_in  = (const float*)d_in[1];
    const float* b_in  = (const float*)d_in[2];
    const float* linW  = (const float*)d_in[3];
    const float* linb  = (const float*)d_in[4];
    const float* qpW   = (const float*)d_in[5];
    const float* qpb   = (const float*)d_in[6];
    const float* entp  = (const float*)d_in[7];
    const float* aqW   = (const float*)d_in[8];
    const float* aqb   = (const float*)d_in[9];
    const float* akW   = (const float*)d_in[10];
    const float* akb   = (const float*)d_in[11];
    const float* attqp = (const float*)d_in[12];
    const float* pparm = (const float*)d_in[13];
    const float* piW   = (const float*)d_in[14];
    const float* pib   = (const float*)d_in[15];
    const float* poW   = (const float*)d_in[16];
    const float* pob   = (const float*)d_in[17];
    const float* outW  = (const float*)d_in[18];
    const float* outb  = (const float*)d_in[19];
    const int*   ei    = (const int*)d_in[20];

    const int N  = in_sizes[0] / 64;   // 20000
    const int E  = in_sizes[20] / 2;   // 300000
    const int EP = E + N;              // self-loops appended

    float* ws     = (float*)d_ws;
    float* h      = ws;
    float* xcomb  = h      + (size_t)N * 128;
    float* xq     = xcomb  + (size_t)N * 128;
    float* qbuf   = xq     + (size_t)N * 4;
    float* kbuf   = qbuf   + (size_t)N * 8;
    float* pq8    = kbuf   + (size_t)N * 8;
    float* escore = pq8    + (size_t)N * 8;
    float* tWin   = escore + EP;
    float* tl0    = tWin   + 64 * 128;
    float* tl1    = tl0    + 128 * 128;
    float* rotbuf = tl1    + 128 * 128;
    float* Mm     = rotbuf + 36 * 8;
    float* vv     = Mm + 128;
    int*   cnt    = (int*)(vv + 32);
    float* sumexp = (float*)(cnt + N);   // 3 slots: [0]=1.0, [1]=layer0, [2]=layer1
    int*   off    = (int*)(sumexp + 4);
    int*   cur    = off + N;
    int*   srcs   = cur + N;
    int*   dsts   = srcs + EP;

    const float* rotE = rotbuf;          // 16 matrices
    const float* rotA = rotbuf + 128;    // 8 matrices
    const float* rotP = rotbuf + 192;    // 12 matrices

    const int nb32 = (N + 31) / 32;
    const int ebl  = (EP + 255) / 256;

    hipMemsetAsync(cnt, 0, (size_t)(N + 4) * sizeof(int), stream);
    k_hist<<<ebl, 256, 0, stream>>>(ei, cnt, E, EP);
    k_scan<<<1, 1024, 0, stream>>>(cnt, off, cur, N);
    k_fill<<<ebl, 256, 0, stream>>>(ei, cur, srcs, dsts, E, EP);
    k_setup<<<1, 256, 0, stream>>>(entp, attqp, pparm, outW, outb, poW, pob,
                                   rotbuf, Mm, vv, sumexp);
    k_tr<<<96, 256, 0, stream>>>(W_in, linW, linW + 128 * 128, tWin, tl0, tl1);
    k_in<<<nb32, 256, 0, stream>>>(x, tWin, b_in, h, N);

    for (int l = 0; l < 2; ++l) {
        const float* tl = (l == 0) ? tl0 : tl1;
        k_ent<<<(N + 255) / 256, 256, 0, stream>>>(h, rotE + l * 64, sumexp + l, xq, N);
        k_lin<<<nb32, 256, 0, stream>>>(h, xq, tl,
            linb + l * 128,
            qpW + (size_t)l * 128 * 4, qpb + l * 128,
            aqW + (size_t)l * 4 * 128, aqb + l * 4,
            akW + (size_t)l * 4 * 128, akb + l * 4,
            sumexp + l, xcomb, qbuf, kbuf, N);
        k_att<<<ebl, 256, 0, stream>>>(qbuf, kbuf, srcs, dsts, rotA + l * 32,
                                       escore, sumexp + l + 1, EP);
        k_gather<<<N, 128, 0, stream>>>(xcomb, srcs, escore, off, cnt, h);
    }

    k_pq<<<(N + 31) / 32, 128, 0, stream>>>(h, piW, pib, sumexp + 2, pq8, N);
    k_pathc<<<(N + 255) / 256, 256, 0, stream>>>(pq8, rotP, Mm, vv, (float*)d_out, N);
}